// Round 1
// baseline (2568.036 us; speedup 1.0000x reference)
//
#include <hip/hip_runtime.h>
#include <hip/hip_bf16.h>

// QLSTM: SEQ=1024, B=64, D_IN=256, D_H=256, fp32 in/out.
// Phase 1: Xp = x @ Wx + bias  (f16 MFMA GEMM, no sequential dep) — unchanged.
// Phase 2: 64 independent recurrences, 1 WG (256 thr, 4 waves, 1 wave/SIMD) per batch.
//   Thread h owns ALL FOUR gate columns {h, 256+h, 512+h, 768+h} -> activation is
//   thread-local: no gate exchange, ONE barrier per step (was 2 + serial half-wave phase).
//   1 wave/EU doubles the VGPR budget (512/thr):
//     Wh rows 0..191  -> VGPRs/AGPRs (4 cols * 24 uint4 = 384 regs)
//     Wh rows 192..255-> LDS (128 KB), read as depth-2 double-buffered pipeline
//                        (issue chunk k+2 while consuming k; latency hidden under dots)
//   hx: one ds_read_b64/lane (lane l holds hx[4l..4l+4)), v_readlane -> SGPR feeding
//       v_dot2_f32_f16; each readlane now feeds 4 dot2s (was 2) -> VALU issue/SIMD drops.
// Round-1 lesson: >256 regs spills at 2 waves/EU (budget 256) — at (256,1) budget is 512.
// Round-2 lesson: streaming weights through L1 costs ~64 B/cyc/CU — must stay resident.
// Round-3 (this): VALU-issue + LDS-pipe bound at 76% busy on active CUs; cut per-SIMD
//   issue via 4-col readlane amortization, kill exchange barriers, pipeline LDS reads.

typedef _Float16 f16;
typedef _Float16 f16x2 __attribute__((ext_vector_type(2)));
typedef _Float16 f16x4 __attribute__((ext_vector_type(4)));
typedef _Float16 f16x8 __attribute__((ext_vector_type(8)));
typedef float f32x4 __attribute__((ext_vector_type(4)));

#define SEQ 1024
#define BATCH 64
#define DIN 256
#define DH 256
#define NCOL 1024
#define RV 192           // rows in VGPRs (24 chunks of 8)
#define RVC 24
#define RLC 8            // LDS chunks (64 rows)

// ---- ws layout (bytes) ----
#define WXP_OFF   0u                 // f16 [32][1024][8]
#define WHV_OFF   524288u            // f16 [1024 cols][192 rows]
#define WHL_OFF   917504u            // f16 [8][1024][8]
#define BIAS_OFF  1048576u           // f32 [1024]
#define HXS_OFF   1052672u           // f16 [64][256]
#define CXS_OFF   1085440u           // f32 [64][256]
#define XP_OFF    1150976u           // f16 [Tc*64][1024]

#define SEQ_LDS_BYTES 132096         // 131072 wts + 1024 hx

__device__ __forceinline__ float dot2(unsigned int h, unsigned int w, float acc) {
#if __has_builtin(__builtin_amdgcn_fdot2)
  return __builtin_amdgcn_fdot2(__builtin_bit_cast(f16x2, h),
                                __builtin_bit_cast(f16x2, w), acc, false);
#else
  f16x2 a = __builtin_bit_cast(f16x2, h);
  f16x2 b = __builtin_bit_cast(f16x2, w);
  return acc + (float)a[0] * (float)b[0] + (float)a[1] * (float)b[1];
#endif
}

__device__ __forceinline__ float fast_sigmoid(float x) {
  float e = __expf(-x);
  return __builtin_amdgcn_rcpf(1.0f + e);
}
__device__ __forceinline__ float fast_tanh(float x) {
  x = fminf(fmaxf(x, -15.0f), 15.0f);
  float e = __expf(2.0f * x);
  return (e - 1.0f) * __builtin_amdgcn_rcpf(e + 1.0f);
}

// ---------------- prep: convert / repack weights ----------------
__global__ void qlstm_prep(const float* __restrict__ Wf, const float* __restrict__ Wi,
                           const float* __restrict__ Wg, const float* __restrict__ Wo,
                           const float* __restrict__ bf_, const float* __restrict__ bi_,
                           const float* __restrict__ bg_, const float* __restrict__ bo_,
                           f16* __restrict__ Wxp, f16* __restrict__ WhV,
                           f16* __restrict__ WhL, float* __restrict__ biasp) {
  int tid = blockIdx.x * 256 + threadIdx.x;
  if (tid < 4 * 512 * 256) {
    int g = tid >> 17;
    int rem = tid & 131071;
    int k = rem >> 8, n = rem & 255;
    const float* W = (g == 0) ? Wf : (g == 1) ? Wi : (g == 2) ? Wg : Wo;
    float v = W[k * 256 + n];
    int j = (g << 8) + n;
    f16 hv = (f16)v;
    if (k < 256) {
      Wxp[((size_t)(k >> 3) * 1024 + j) * 8 + (k & 7)] = hv;
    } else {
      int kk = k - 256;
      if (kk < RV) {
        WhV[(size_t)j * RV + kk] = hv;
      } else {
        int r = kk - RV;
        WhL[((size_t)(r >> 3) * 1024 + j) * 8 + (r & 7)] = hv;
      }
    }
  }
  if (tid < 1024) {
    int g = tid >> 8, n = tid & 255;
    const float* bb = (g == 0) ? bf_ : (g == 1) ? bi_ : (g == 2) ? bg_ : bo_;
    biasp[tid] = bb[n];
  }
}

// ---------------- phase 1: Xp = x @ Wx + bias  (MFMA f16) ----------------
__global__ __launch_bounds__(256) void qlstm_xproj(
    const float* __restrict__ X, const f16* __restrict__ Wxp,
    const float* __restrict__ biasp, f16* __restrict__ Xp) {
  __shared__ f16 As[128][72];
  __shared__ f16 Bs[8 * 128 * 8];

  int tid = threadIdx.x;
  int tm = blockIdx.x, tn = blockIdx.y;
  int wave = tid >> 6, lane = tid & 63;
  int qm = (wave & 1) * 64, qn = (wave >> 1) * 64;
  int lm = lane & 15, lk = lane >> 4;

  f32x4 acc[4][4];
#pragma unroll
  for (int a = 0; a < 4; ++a)
#pragma unroll
    for (int b = 0; b < 4; ++b) acc[a][b] = (f32x4)0.0f;

  for (int k0 = 0; k0 < 256; k0 += 64) {
    {
      int r = tid >> 1, c0 = (tid & 1) * 32;
      const float4* src = (const float4*)(X + (size_t)(tm * 128 + r) * 256 + k0 + c0);
#pragma unroll
      for (int i = 0; i < 8; ++i) {
        float4 v = src[i];
        f16x4 pk = {(f16)v.x, (f16)v.y, (f16)v.z, (f16)v.w};
        *(f16x4*)&As[r][c0 + i * 4] = pk;
      }
    }
    {
#pragma unroll
      for (int it = 0; it < 4; ++it) {
        int idx = it * 256 + tid;
        int kgi = idx >> 7, n = idx & 127;
        ((uint4*)Bs)[idx] =
            *(const uint4*)(Wxp + (((size_t)(k0 >> 3) + kgi) * 1024 + tn * 128 + n) * 8);
      }
    }
    __syncthreads();
#pragma unroll
    for (int ks = 0; ks < 2; ++ks) {
      f16x8 af[4], bfr[4];
#pragma unroll
      for (int mi = 0; mi < 4; ++mi)
        af[mi] = *(const f16x8*)&As[qm + mi * 16 + lm][ks * 32 + lk * 8];
#pragma unroll
      for (int ni = 0; ni < 4; ++ni)
        bfr[ni] = *(const f16x8*)&Bs[(((ks * 4 + lk) * 128) + qn + ni * 16 + lm) * 8];
#pragma unroll
      for (int mi = 0; mi < 4; ++mi)
#pragma unroll
        for (int ni = 0; ni < 4; ++ni)
          acc[mi][ni] = __builtin_amdgcn_mfma_f32_16x16x32_f16(af[mi], bfr[ni],
                                                               acc[mi][ni], 0, 0, 0);
    }
    __syncthreads();
  }
  int m0 = tm * 128 + qm, j0 = tn * 128 + qn;
#pragma unroll
  for (int mi = 0; mi < 4; ++mi)
#pragma unroll
    for (int ni = 0; ni < 4; ++ni) {
      int j = j0 + ni * 16 + lm;
      float bv = biasp[j];
#pragma unroll
      for (int r = 0; r < 4; ++r) {
        int m = m0 + mi * 16 + lk * 4 + r;
        Xp[(size_t)m * 1024 + j] = (f16)(acc[mi][ni][r] + bv);
      }
    }
}

// ---------------- phase 2: sequential LSTM ----------------
// Reg chunk c (rows 8c..8c+7), all 4 gate columns:
#define RCH(c)                                                                \
  do {                                                                        \
    unsigned s0 = (unsigned)__builtin_amdgcn_readlane((int)hl.x, 2 * (c));    \
    unsigned s1 = (unsigned)__builtin_amdgcn_readlane((int)hl.y, 2 * (c));    \
    unsigned s2 = (unsigned)__builtin_amdgcn_readlane((int)hl.x, 2 * (c) + 1);\
    unsigned s3 = (unsigned)__builtin_amdgcn_readlane((int)hl.y, 2 * (c) + 1);\
    a0 = dot2(s0, wreg[0][c].x, a0); a0 = dot2(s1, wreg[0][c].y, a0);         \
    a0 = dot2(s2, wreg[0][c].z, a0); a0 = dot2(s3, wreg[0][c].w, a0);         \
    a1 = dot2(s0, wreg[1][c].x, a1); a1 = dot2(s1, wreg[1][c].y, a1);         \
    a1 = dot2(s2, wreg[1][c].z, a1); a1 = dot2(s3, wreg[1][c].w, a1);         \
    a2 = dot2(s0, wreg[2][c].x, a2); a2 = dot2(s1, wreg[2][c].y, a2);         \
    a2 = dot2(s2, wreg[2][c].z, a2); a2 = dot2(s3, wreg[2][c].w, a2);         \
    a3 = dot2(s0, wreg[3][c].x, a3); a3 = dot2(s1, wreg[3][c].y, a3);         \
    a3 = dot2(s2, wreg[3][c].z, a3); a3 = dot2(s3, wreg[3][c].w, a3);         \
  } while (0)

// Issue LDS chunk c (4 gate columns) into landing regs:
#define LISS(P0, P1, P2, P3, c)                                               \
  do {                                                                        \
    P0 = wl[(c) * 1024 + 0];   P1 = wl[(c) * 1024 + 256];                     \
    P2 = wl[(c) * 1024 + 512]; P3 = wl[(c) * 1024 + 768];                     \
  } while (0)

// Consume landed LDS chunk (global chunk index cc = 24 + c):
#define LCONS(P0, P1, P2, P3, cc)                                             \
  do {                                                                        \
    unsigned s0 = (unsigned)__builtin_amdgcn_readlane((int)hl.x, 2 * (cc));   \
    unsigned s1 = (unsigned)__builtin_amdgcn_readlane((int)hl.y, 2 * (cc));   \
    unsigned s2 = (unsigned)__builtin_amdgcn_readlane((int)hl.x, 2 * (cc) + 1);\
    unsigned s3 = (unsigned)__builtin_amdgcn_readlane((int)hl.y, 2 * (cc) + 1);\
    a0 = dot2(s0, P0.x, a0); a0 = dot2(s1, P0.y, a0);                         \
    a0 = dot2(s2, P0.z, a0); a0 = dot2(s3, P0.w, a0);                         \
    a1 = dot2(s0, P1.x, a1); a1 = dot2(s1, P1.y, a1);                         \
    a1 = dot2(s2, P1.z, a1); a1 = dot2(s3, P1.w, a1);                         \
    a2 = dot2(s0, P2.x, a2); a2 = dot2(s1, P2.y, a2);                         \
    a2 = dot2(s2, P2.z, a2); a2 = dot2(s3, P2.w, a2);                         \
    a3 = dot2(s0, P3.x, a3); a3 = dot2(s1, P3.y, a3);                         \
    a3 = dot2(s2, P3.z, a3); a3 = dot2(s3, P3.w, a3);                         \
  } while (0)

__global__ __launch_bounds__(256, 1) void qlstm_seq(
    const f16* __restrict__ Xp, const f16* __restrict__ WhV,
    const f16* __restrict__ WhL,
    float* __restrict__ out, f16* __restrict__ hxs, float* __restrict__ cxs,
    float* __restrict__ hxout, float* __restrict__ cxout, int t0, int t1) {
  extern __shared__ char smem[];
  f16* wlds = (f16*)smem;                 // 131072 B: [8][1024][8]
  f16* hxb = (f16*)(smem + 131072);       // [2][256]

  int h = threadIdx.x;                    // 0..255, owns output column h
  int lane = h & 63;
  int b = blockIdx.x;

  // stage LDS weights (8192 uint4 over 256 threads)
  {
    const uint4* src = (const uint4*)WhL;
    uint4* dst = (uint4*)wlds;
#pragma unroll
    for (int i = 0; i < 32; ++i) dst[i * 256 + h] = src[i * 256 + h];
  }

  // Register-resident weights: 4 gate-cols x 24 uint4 = 384 regs
  uint4 wreg[4][RVC];
#pragma unroll
  for (int g = 0; g < 4; ++g) {
    const uint4* q = (const uint4*)WhV + (size_t)(g * 256 + h) * RVC;
#pragma unroll
    for (int c = 0; c < RVC; ++c) wreg[g][c] = q[c];
  }

  float cx = 0.0f;
  int par0 = t0 & 1;
  if (t0 == 0) {
    hxb[par0 * 256 + h] = (f16)0.0f;
  } else {
    hxb[par0 * 256 + h] = hxs[b * 256 + h];
    cx = cxs[b * 256 + h];
  }

  const f16* xpb = Xp + (size_t)b * 1024;
  f16 x0 = xpb[h], x1 = xpb[256 + h], x2 = xpb[512 + h], x3 = xpb[768 + h];

  const uint4* wl = (const uint4*)wlds + h;

  __syncthreads();

  float hv = 0.0f;
  for (int t = t0; t < t1; ++t) {
    int par = t & 1;
    // whole hx into the wave: lane l holds hx[4l..4l+4)
    uint2 hl = *(const uint2*)(hxb + par * 256 + lane * 4);

    float a0 = (float)x0, a1 = (float)x1, a2 = (float)x2, a3 = (float)x3;

    // prefetch next step's Xp (independent of recurrence)
    int tnx = (t + 1 < t1) ? (t + 1 - t0) : (t - t0);
    const f16* xq = Xp + ((size_t)tnx * BATCH + b) * 1024;
    f16 nx0 = xq[h], nx1 = xq[256 + h], nx2 = xq[512 + h], nx3 = xq[768 + h];

    // depth-2 pipelined LDS chunks interleaved with register chunks
    uint4 A0, A1, A2, A3, B0, B1, B2, B3;
    LISS(A0, A1, A2, A3, 0);
    LISS(B0, B1, B2, B3, 1);
    RCH(0); RCH(1); RCH(2);
    LCONS(A0, A1, A2, A3, 24); LISS(A0, A1, A2, A3, 2);
    RCH(3); RCH(4); RCH(5);
    LCONS(B0, B1, B2, B3, 25); LISS(B0, B1, B2, B3, 3);
    RCH(6); RCH(7); RCH(8);
    LCONS(A0, A1, A2, A3, 26); LISS(A0, A1, A2, A3, 4);
    RCH(9); RCH(10); RCH(11);
    LCONS(B0, B1, B2, B3, 27); LISS(B0, B1, B2, B3, 5);
    RCH(12); RCH(13); RCH(14);
    LCONS(A0, A1, A2, A3, 28); LISS(A0, A1, A2, A3, 6);
    RCH(15); RCH(16); RCH(17);
    LCONS(B0, B1, B2, B3, 29); LISS(B0, B1, B2, B3, 7);
    RCH(18); RCH(19); RCH(20);
    LCONS(A0, A1, A2, A3, 30);
    RCH(21); RCH(22); RCH(23);
    LCONS(B0, B1, B2, B3, 31);

    // thread-local activation: all four gates live here, no exchange needed
    float vf = fast_sigmoid(a0);
    float vi = fast_sigmoid(a1);
    float vg = fast_tanh(a2);
    float vo = fast_sigmoid(a3);
    cx = fmaf(vf, cx, vi * vg);
    hv = vo * fast_tanh(cx);
    out[((size_t)t * BATCH + b) * 256 + h] = hv;
    hxb[(par ^ 1) * 256 + h] = (f16)hv;
    __syncthreads();

    x0 = nx0; x1 = nx1; x2 = nx2; x3 = nx3;
  }

  hxs[b * 256 + h] = (f16)hv;
  cxs[b * 256 + h] = cx;
  if (t1 == SEQ) {
    hxout[b * 256 + h] = hv;
    cxout[b * 256 + h] = cx;
  }
}

extern "C" void kernel_launch(void* const* d_in, const int* in_sizes, int n_in,
                              void* d_out, int out_size, void* d_ws, size_t ws_size,
                              hipStream_t stream) {
  const float* X  = (const float*)d_in[0];
  const float* Wf = (const float*)d_in[1]; const float* bf_ = (const float*)d_in[2];
  const float* Wi = (const float*)d_in[3]; const float* bi_ = (const float*)d_in[4];
  const float* Wg = (const float*)d_in[5]; const float* bg_ = (const float*)d_in[6];
  const float* Wo = (const float*)d_in[7]; const float* bo_ = (const float*)d_in[8];
  float* out = (float*)d_out;

  char* ws = (char*)d_ws;
  f16*   Wxp   = (f16*)(ws + WXP_OFF);
  f16*   WhV   = (f16*)(ws + WHV_OFF);
  f16*   WhL   = (f16*)(ws + WHL_OFF);
  float* biasp = (float*)(ws + BIAS_OFF);
  f16*   hxs   = (f16*)(ws + HXS_OFF);
  float* cxs   = (float*)(ws + CXS_OFF);
  f16*   Xp    = (f16*)(ws + XP_OFF);

  size_t avail = (ws_size > XP_OFF) ? (ws_size - XP_OFF) : 0;
  int Tc = SEQ;
  while (Tc > 2 && (size_t)Tc * BATCH * NCOL * 2 > avail) Tc >>= 1;

  qlstm_prep<<<2048, 256, 0, stream>>>(Wf, Wi, Wg, Wo, bf_, bi_, bg_, bo_,
                                       Wxp, WhV, WhL, biasp);

  (void)hipFuncSetAttribute((const void*)qlstm_seq,
                            hipFuncAttributeMaxDynamicSharedMemorySize,
                            SEQ_LDS_BYTES);

  float* hxout = out + (size_t)SEQ * BATCH * DH;
  float* cxout = hxout + BATCH * DH;

  for (int t0 = 0; t0 < SEQ; t0 += Tc) {
    dim3 g1(Tc * BATCH / 128, NCOL / 128);
    qlstm_xproj<<<g1, 256, 0, stream>>>(X + (size_t)t0 * BATCH * DIN, Wxp, biasp, Xp);
    qlstm_seq<<<BATCH, 256, SEQ_LDS_BYTES, stream>>>(Xp, WhV, WhL, out, hxs, cxs,
                                                     hxout, cxout, t0, t0 + Tc);
  }
}

// Round 2
// 1997.070 us; speedup vs baseline: 1.2859x; 1.2859x over previous
//
#include <hip/hip_runtime.h>
#include <hip/hip_bf16.h>

// QLSTM: SEQ=1024, B=64, D_IN=256, D_H=256, fp32 in/out.
// Phase 1: Xp = x @ Wx + bias  (f16 MFMA GEMM, no sequential dep) — unchanged.
// Phase 2: 64 independent recurrences, 1 WG (512 thr, 8 waves, 2 waves/SIMD) per batch.
//   Gate pairing is SAME-WAVE: wave w, lane l -> h = w*32 + (l&31), p = l>>5.
//   p=0 lanes own cols {h, h+256} (f,i); p=1 lanes own {512+h, 768+h} (g,o).
//   Gate exchange = 2x __shfl_xor(.,32) in-register (no LDS roundtrip, no 2nd barrier);
//   activation computed redundantly on both partner lanes; lane<32 writes results.
//   Wh rows 0..183  -> arch VGPRs (2 cols * 23 uint4 = 184 regs).
//     amdgpu_waves_per_eu(2,2): budget 256/wave so weights are GENUINELY arch-resident
//     (round-0's VGPR_Count=128 proved the compiler was AGPR-shuffling them: with
//      extern-shared it can't see the 148KB LDS and targets 4 waves/SIMD).
//   Wh rows 184..255-> LDS (144 KB), depth-2 pipelined (LISS ahead / LCONS behind).
//   Per-step barrier = raw "s_waitcnt lgkmcnt(0); s_barrier" — __syncthreads() would
//   drain vmcnt(0), serializing the out-store + Xp prefetch into every step.
// Round-1 lesson: arch VGPRs cap at 256; >that goes to AGPR (v_accvgpr_read per use)
//   or scratch. 4-col/thread mapping is therefore structurally reg-starved.

typedef _Float16 f16;
typedef _Float16 f16x2 __attribute__((ext_vector_type(2)));
typedef _Float16 f16x4 __attribute__((ext_vector_type(4)));
typedef _Float16 f16x8 __attribute__((ext_vector_type(8)));
typedef float f32x4 __attribute__((ext_vector_type(4)));

#define SEQ 1024
#define BATCH 64
#define DIN 256
#define DH 256
#define NCOL 1024
#define RV 184           // rows in VGPRs (23 chunks of 8)
#define RVC 23
#define RLC 9            // LDS chunks (72 rows)

// ---- ws layout (bytes) ----
#define WXP_OFF   0u                 // f16 [32][1024][8]
#define WHV_OFF   524288u            // f16 [1024 cols][184 rows]
#define WHL_OFF   901120u            // f16 [9][1024][8]
#define BIAS_OFF  1048576u           // f32 [1024]
#define HXS_OFF   1052672u           // f16 [64][256]
#define CXS_OFF   1085440u           // f32 [64][256]
#define XP_OFF    1150976u           // f16 [Tc*64][1024]

#define SEQ_LDS_BYTES 148480         // 147456 wts + 1024 hx

__device__ __forceinline__ float dot2(unsigned int h, unsigned int w, float acc) {
#if __has_builtin(__builtin_amdgcn_fdot2)
  return __builtin_amdgcn_fdot2(__builtin_bit_cast(f16x2, h),
                                __builtin_bit_cast(f16x2, w), acc, false);
#else
  f16x2 a = __builtin_bit_cast(f16x2, h);
  f16x2 b = __builtin_bit_cast(f16x2, w);
  return acc + (float)a[0] * (float)b[0] + (float)a[1] * (float)b[1];
#endif
}

__device__ __forceinline__ float fast_sigmoid(float x) {
  float e = __expf(-x);
  return __builtin_amdgcn_rcpf(1.0f + e);
}
__device__ __forceinline__ float fast_tanh(float x) {
  x = fminf(fmaxf(x, -15.0f), 15.0f);
  float e = __expf(2.0f * x);
  return (e - 1.0f) * __builtin_amdgcn_rcpf(e + 1.0f);
}

// LDS-only barrier: does NOT drain vmcnt (out-store / Xp prefetch ride across).
__device__ __forceinline__ void lds_barrier() {
  asm volatile("s_waitcnt lgkmcnt(0)\n\ts_barrier" ::: "memory");
}

// ---------------- prep: convert / repack weights ----------------
__global__ void qlstm_prep(const float* __restrict__ Wf, const float* __restrict__ Wi,
                           const float* __restrict__ Wg, const float* __restrict__ Wo,
                           const float* __restrict__ bf_, const float* __restrict__ bi_,
                           const float* __restrict__ bg_, const float* __restrict__ bo_,
                           f16* __restrict__ Wxp, f16* __restrict__ WhV,
                           f16* __restrict__ WhL, float* __restrict__ biasp) {
  int tid = blockIdx.x * 256 + threadIdx.x;
  if (tid < 4 * 512 * 256) {
    int g = tid >> 17;
    int rem = tid & 131071;
    int k = rem >> 8, n = rem & 255;
    const float* W = (g == 0) ? Wf : (g == 1) ? Wi : (g == 2) ? Wg : Wo;
    float v = W[k * 256 + n];
    int j = (g << 8) + n;
    f16 hv = (f16)v;
    if (k < 256) {
      Wxp[((size_t)(k >> 3) * 1024 + j) * 8 + (k & 7)] = hv;
    } else {
      int kk = k - 256;
      if (kk < RV) {
        WhV[(size_t)j * RV + kk] = hv;
      } else {
        int r = kk - RV;
        WhL[((size_t)(r >> 3) * 1024 + j) * 8 + (r & 7)] = hv;
      }
    }
  }
  if (tid < 1024) {
    int g = tid >> 8, n = tid & 255;
    const float* bb = (g == 0) ? bf_ : (g == 1) ? bi_ : (g == 2) ? bg_ : bo_;
    biasp[tid] = bb[n];
  }
}

// ---------------- phase 1: Xp = x @ Wx + bias  (MFMA f16) ----------------
__global__ __launch_bounds__(256) void qlstm_xproj(
    const float* __restrict__ X, const f16* __restrict__ Wxp,
    const float* __restrict__ biasp, f16* __restrict__ Xp) {
  __shared__ f16 As[128][72];
  __shared__ f16 Bs[8 * 128 * 8];

  int tid = threadIdx.x;
  int tm = blockIdx.x, tn = blockIdx.y;
  int wave = tid >> 6, lane = tid & 63;
  int qm = (wave & 1) * 64, qn = (wave >> 1) * 64;
  int lm = lane & 15, lk = lane >> 4;

  f32x4 acc[4][4];
#pragma unroll
  for (int a = 0; a < 4; ++a)
#pragma unroll
    for (int b = 0; b < 4; ++b) acc[a][b] = (f32x4)0.0f;

  for (int k0 = 0; k0 < 256; k0 += 64) {
    {
      int r = tid >> 1, c0 = (tid & 1) * 32;
      const float4* src = (const float4*)(X + (size_t)(tm * 128 + r) * 256 + k0 + c0);
#pragma unroll
      for (int i = 0; i < 8; ++i) {
        float4 v = src[i];
        f16x4 pk = {(f16)v.x, (f16)v.y, (f16)v.z, (f16)v.w};
        *(f16x4*)&As[r][c0 + i * 4] = pk;
      }
    }
    {
#pragma unroll
      for (int it = 0; it < 4; ++it) {
        int idx = it * 256 + tid;
        int kgi = idx >> 7, n = idx & 127;
        ((uint4*)Bs)[idx] =
            *(const uint4*)(Wxp + (((size_t)(k0 >> 3) + kgi) * 1024 + tn * 128 + n) * 8);
      }
    }
    __syncthreads();
#pragma unroll
    for (int ks = 0; ks < 2; ++ks) {
      f16x8 af[4], bfr[4];
#pragma unroll
      for (int mi = 0; mi < 4; ++mi)
        af[mi] = *(const f16x8*)&As[qm + mi * 16 + lm][ks * 32 + lk * 8];
#pragma unroll
      for (int ni = 0; ni < 4; ++ni)
        bfr[ni] = *(const f16x8*)&Bs[(((ks * 4 + lk) * 128) + qn + ni * 16 + lm) * 8];
#pragma unroll
      for (int mi = 0; mi < 4; ++mi)
#pragma unroll
        for (int ni = 0; ni < 4; ++ni)
          acc[mi][ni] = __builtin_amdgcn_mfma_f32_16x16x32_f16(af[mi], bfr[ni],
                                                               acc[mi][ni], 0, 0, 0);
    }
    __syncthreads();
  }
  int m0 = tm * 128 + qm, j0 = tn * 128 + qn;
#pragma unroll
  for (int mi = 0; mi < 4; ++mi)
#pragma unroll
    for (int ni = 0; ni < 4; ++ni) {
      int j = j0 + ni * 16 + lm;
      float bv = biasp[j];
#pragma unroll
      for (int r = 0; r < 4; ++r) {
        int m = m0 + mi * 16 + lk * 4 + r;
        Xp[(size_t)m * 1024 + j] = (f16)(acc[mi][ni][r] + bv);
      }
    }
}

// ---------------- phase 2: sequential LSTM ----------------
// Register chunk c (rows 8c..8c+7), this thread's 2 cols:
#define RCH(c)                                                                \
  do {                                                                        \
    unsigned s0 = (unsigned)__builtin_amdgcn_readlane((int)hl.x, 2 * (c));    \
    unsigned s1 = (unsigned)__builtin_amdgcn_readlane((int)hl.y, 2 * (c));    \
    unsigned s2 = (unsigned)__builtin_amdgcn_readlane((int)hl.x, 2 * (c) + 1);\
    unsigned s3 = (unsigned)__builtin_amdgcn_readlane((int)hl.y, 2 * (c) + 1);\
    a0 = dot2(s0, wr0[c].x, a0); a0 = dot2(s1, wr0[c].y, a0);                 \
    a0 = dot2(s2, wr0[c].z, a0); a0 = dot2(s3, wr0[c].w, a0);                 \
    a1 = dot2(s0, wr1[c].x, a1); a1 = dot2(s1, wr1[c].y, a1);                 \
    a1 = dot2(s2, wr1[c].z, a1); a1 = dot2(s3, wr1[c].w, a1);                 \
  } while (0)

// Issue LDS chunk c into landing regs (2 cols):
#define LISS(P0, P1, c)                                                       \
  do {                                                                        \
    P0 = wl[(c) * 1024];                                                      \
    P1 = wl[(c) * 1024 + 256];                                                \
  } while (0)

// Consume landed LDS chunk (global chunk index cc = 23 + c):
#define LCONS(P0, P1, cc)                                                     \
  do {                                                                        \
    unsigned s0 = (unsigned)__builtin_amdgcn_readlane((int)hl.x, 2 * (cc));   \
    unsigned s1 = (unsigned)__builtin_amdgcn_readlane((int)hl.y, 2 * (cc));   \
    unsigned s2 = (unsigned)__builtin_amdgcn_readlane((int)hl.x, 2 * (cc) + 1);\
    unsigned s3 = (unsigned)__builtin_amdgcn_readlane((int)hl.y, 2 * (cc) + 1);\
    a0 = dot2(s0, P0.x, a0); a0 = dot2(s1, P0.y, a0);                         \
    a0 = dot2(s2, P0.z, a0); a0 = dot2(s3, P0.w, a0);                         \
    a1 = dot2(s0, P1.x, a1); a1 = dot2(s1, P1.y, a1);                         \
    a1 = dot2(s2, P1.z, a1); a1 = dot2(s3, P1.w, a1);                         \
  } while (0)

__global__ __launch_bounds__(512)
__attribute__((amdgpu_waves_per_eu(2, 2))) void qlstm_seq(
    const f16* __restrict__ Xp, const f16* __restrict__ WhV,
    const f16* __restrict__ WhL,
    float* __restrict__ out, f16* __restrict__ hxs, float* __restrict__ cxs,
    float* __restrict__ hxout, float* __restrict__ cxout, int t0, int t1) {
  extern __shared__ char smem[];
  f16* wlds = (f16*)smem;                 // 147456 B: [9][1024][8]
  f16* hxb = (f16*)(smem + 147456);       // [2][256]

  int tid = threadIdx.x;
  int wave = tid >> 6, lane = tid & 63;
  int p = lane >> 5;                      // gate-pair id within the wave
  int h = (wave << 5) + (lane & 31);      // output column this thread serves
  int b = blockIdx.x;
  int j0 = p * 512 + h;                   // p=0: f-col; p=1: g-col
  // j1 = j0 + 256                        // p=0: i-col; p=1: o-col
  bool lo = (lane < 32);

  // stage LDS weights (9216 uint4 over 512 threads)
  {
    const uint4* src = (const uint4*)WhL;
    uint4* dst = (uint4*)wlds;
#pragma unroll
    for (int i = 0; i < 18; ++i) dst[i * 512 + tid] = src[i * 512 + tid];
  }

  // arch-VGPR-resident weights: 2 cols x 23 uint4 = 184 regs
  uint4 wr0[RVC], wr1[RVC];
  {
    const uint4* q0 = (const uint4*)WhV + (size_t)j0 * RVC;
    const uint4* q1 = (const uint4*)WhV + (size_t)(j0 + 256) * RVC;
#pragma unroll
    for (int c = 0; c < RVC; ++c) { wr0[c] = q0[c]; wr1[c] = q1[c]; }
  }

  float cx = 0.0f;
  int par0 = t0 & 1;
  if (t0 == 0) {
    if (lo) hxb[par0 * 256 + h] = (f16)0.0f;
  } else {
    if (lo) hxb[par0 * 256 + h] = hxs[b * 256 + h];
    cx = cxs[b * 256 + h];               // both partner lanes carry cx
  }

  const f16* xpb = Xp + (size_t)b * 1024;
  f16 xa = xpb[j0], xb_ = xpb[j0 + 256];

  const uint4* wl = (const uint4*)wlds + j0;

  __syncthreads();

  float hv = 0.0f;
  for (int t = t0; t < t1; ++t) {
    int par = t & 1;
    // whole hx into the wave: lane l holds hx[4l..4l+4)
    uint2 hl = *(const uint2*)(hxb + par * 256 + lane * 4);

    float a0 = (float)xa, a1 = (float)xb_;

    // prefetch next step's Xp (independent of recurrence; never drained in-loop)
    int tnx = (t + 1 < t1) ? (t + 1 - t0) : (t - t0);
    const f16* xq = Xp + ((size_t)tnx * BATCH + b) * 1024;
    f16 xna = xq[j0], xnb = xq[j0 + 256];

    // depth-2 pipelined LDS chunks interleaved with register chunks
    uint4 A0, A1, B0, B1;
    LISS(A0, A1, 0);
    LISS(B0, B1, 1);
    RCH(0); RCH(1);
    LCONS(A0, A1, 23); LISS(A0, A1, 2);
    RCH(2); RCH(3);
    LCONS(B0, B1, 24); LISS(B0, B1, 3);
    RCH(4); RCH(5);
    LCONS(A0, A1, 25); LISS(A0, A1, 4);
    RCH(6); RCH(7);
    LCONS(B0, B1, 26); LISS(B0, B1, 5);
    RCH(8); RCH(9);
    LCONS(A0, A1, 27); LISS(A0, A1, 6);
    RCH(10); RCH(11);
    LCONS(B0, B1, 28); LISS(B0, B1, 7);
    RCH(12); RCH(13);
    LCONS(A0, A1, 29); LISS(A0, A1, 8);
    RCH(14); RCH(15);
    LCONS(B0, B1, 30);
    RCH(16); RCH(17);
    LCONS(A0, A1, 31);
    RCH(18); RCH(19); RCH(20); RCH(21); RCH(22);

    // in-wave gate exchange: partner lane (lane^32) has the other 2 gates
    float r0 = __shfl_xor(a0, 32, 64);
    float r1 = __shfl_xor(a1, 32, 64);
    float pf = lo ? a0 : r0;
    float pi = lo ? a1 : r1;
    float pg = lo ? r0 : a0;
    float po = lo ? r1 : a1;

    float vf = fast_sigmoid(pf);
    float vi = fast_sigmoid(pi);
    float vg = fast_tanh(pg);
    float vo = fast_sigmoid(po);
    cx = fmaf(vf, cx, vi * vg);           // both partner lanes keep cx
    hv = vo * fast_tanh(cx);
    if (lo) {
      out[((size_t)t * BATCH + b) * 256 + h] = hv;
      hxb[(par ^ 1) * 256 + h] = (f16)hv;
    }
    lds_barrier();                        // lgkmcnt(0) + s_barrier, NO vmcnt drain

    xa = xna; xb_ = xnb;
  }

  if (lo) {
    hxs[b * 256 + h] = (f16)hv;
    cxs[b * 256 + h] = cx;
    if (t1 == SEQ) {
      hxout[b * 256 + h] = hv;
      cxout[b * 256 + h] = cx;
    }
  }
}

extern "C" void kernel_launch(void* const* d_in, const int* in_sizes, int n_in,
                              void* d_out, int out_size, void* d_ws, size_t ws_size,
                              hipStream_t stream) {
  const float* X  = (const float*)d_in[0];
  const float* Wf = (const float*)d_in[1]; const float* bf_ = (const float*)d_in[2];
  const float* Wi = (const float*)d_in[3]; const float* bi_ = (const float*)d_in[4];
  const float* Wg = (const float*)d_in[5]; const float* bg_ = (const float*)d_in[6];
  const float* Wo = (const float*)d_in[7]; const float* bo_ = (const float*)d_in[8];
  float* out = (float*)d_out;

  char* ws = (char*)d_ws;
  f16*   Wxp   = (f16*)(ws + WXP_OFF);
  f16*   WhV   = (f16*)(ws + WHV_OFF);
  f16*   WhL   = (f16*)(ws + WHL_OFF);
  float* biasp = (float*)(ws + BIAS_OFF);
  f16*   hxs   = (f16*)(ws + HXS_OFF);
  float* cxs   = (float*)(ws + CXS_OFF);
  f16*   Xp    = (f16*)(ws + XP_OFF);

  size_t avail = (ws_size > XP_OFF) ? (ws_size - XP_OFF) : 0;
  int Tc = SEQ;
  while (Tc > 2 && (size_t)Tc * BATCH * NCOL * 2 > avail) Tc >>= 1;

  qlstm_prep<<<2048, 256, 0, stream>>>(Wf, Wi, Wg, Wo, bf_, bi_, bg_, bo_,
                                       Wxp, WhV, WhL, biasp);

  (void)hipFuncSetAttribute((const void*)qlstm_seq,
                            hipFuncAttributeMaxDynamicSharedMemorySize,
                            SEQ_LDS_BYTES);

  float* hxout = out + (size_t)SEQ * BATCH * DH;
  float* cxout = hxout + BATCH * DH;

  for (int t0 = 0; t0 < SEQ; t0 += Tc) {
    dim3 g1(Tc * BATCH / 128, NCOL / 128);
    qlstm_xproj<<<g1, 256, 0, stream>>>(X + (size_t)t0 * BATCH * DIN, Wxp, biasp, Xp);
    qlstm_seq<<<BATCH, 512, SEQ_LDS_BYTES, stream>>>(Xp, WhV, WhL, out, hxs, cxs,
                                                     hxout, cxout, t0, t0 + Tc);
  }
}